// Round 6
// baseline (85.773 us; speedup 1.0000x reference)
//
#include <hip/hip_runtime.h>

// ElementalGTOLogNormalSkinCutoff on MI355X (gfx950) — round 6
//
// Two-phase: phase 1 bucket-sorts per-neighbour records by species into LDS
// (count pass + build pass, no register buffering); phase 2 assigns each
// thread an (atom, gaussian-PAIR) — halving LDS record re-reads (the round-5
// bottleneck: ~492k ds_reads ≈ 7 us of LDS-issue/CU) and halving store
// instructions via dwordx2 on the g-contiguous output layout.
//
// Record: P=(c0,c1,c2,ux), Q=(uy,uz) with rad = exp2(c0*lo^2 + c1*lo + c2),
// c0=-0.5*log2e/sigma2, c1=-2*c0*mu, c2=c0*mu^2+log2(amp),
// amp = rsqrt(sigma2)*cut/d^2 clamped to 1e-30 (cut can be ~-1e-7 at d~6).

#define B_   128
#define N_   128
#define M_   64
#define NG_  20
#define NSP_ 4
#define FPSIZE_ 600
#define APB  32                     // atoms per block (divides N_, so b uniform)
#define NTASK (APB * M_)            // 2048 neighbour slots per block
#define BLOCK_THREADS 320           // = APB * 10 g-pairs = 5 waves exactly

__global__ __launch_bounds__(BLOCK_THREADS)
void gto_fp_kernel(const float* __restrict__ coords,   // [B,N,3]
                   const int*   __restrict__ charges,  // [B,N]
                   const int*   __restrict__ counts,   // [B]
                   const int*   __restrict__ neigh,    // [B,N,M]
                   float*       __restrict__ out)      // [B,N,600]
{
    __shared__ float4 sP[APB][M_ + 1];      // c0, c1, c2, ux  (padded row)
    __shared__ float2 sQ[APB][M_ + 1];      // uy, uz          (padded row)
    __shared__ int s_cnt[APB][NSP_];
    __shared__ int s_start[APB][NSP_];
    __shared__ int s_pos[APB][NSP_];

    const int tid = threadIdx.x;
    const int blockBase = blockIdx.x * APB;
    const int bidx = blockBase / N_;        // uniform: APB divides N_

    if (tid < APB * NSP_) ((int*)s_cnt)[tid] = 0;
    __syncthreads();

    // -------- phase 1a: count species per atom (cheap: neigh + charge) ----
    for (int t = tid; t < NTASK; t += BLOCK_THREADS) {
        const int la = t >> 6, m = t & 63;
        const int nb = neigh[(blockBase + la) * M_ + m];
        if (nb >= 0) {
            const int z = charges[bidx * N_ + nb];
            const int s = (z == 1) ? 0 : (z - 5);   // {1,6,7,8} -> {0,1,2,3}
            atomicAdd(&s_cnt[la][s], 1);
        }
    }
    __syncthreads();

    if (tid < APB) {
        const int c0 = s_cnt[tid][0], c1 = s_cnt[tid][1], c2 = s_cnt[tid][2];
        s_start[tid][0] = 0;            s_pos[tid][0] = 0;
        s_start[tid][1] = c0;           s_pos[tid][1] = c0;
        s_start[tid][2] = c0 + c1;      s_pos[tid][2] = c0 + c1;
        s_start[tid][3] = c0 + c1 + c2; s_pos[tid][3] = c0 + c1 + c2;
    }
    __syncthreads();

    // -------- phase 1b: build records straight into sorted slots ----------
    for (int t = tid; t < NTASK; t += BLOCK_THREADS) {
        const int la = t >> 6, m = t & 63;
        const int atom = blockBase + la;
        const int nb = neigh[atom * M_ + m];
        if (nb < 0) continue;
        const int nidx = bidx * N_ + nb;
        const float dx = coords[atom * 3 + 0] - coords[nidx * 3 + 0];
        const float dy = coords[atom * 3 + 1] - coords[nidx * 3 + 1];
        const float dz = coords[atom * 3 + 2] - coords[nidx * 3 + 2];
        const int   z  = charges[nidx];

        const float d2     = dx * dx + dy * dy + dz * dz;
        const float inv_d  = __builtin_amdgcn_rsqf(d2);
        const float d      = d2 * inv_d;
        const float inv_d2 = inv_d * inv_d;

        const float dsw  = (d - 1.0f) * 0.2f;
        const float dsw2 = dsw * dsw;
        const float cut  = 1.0f - dsw2 * dsw * fmaf(6.0f, dsw2, fmaf(-15.0f, dsw, 10.0f));

        const float sigma2 = __logf(fmaf(2.0f, inv_d2, 1.0f));     // log(1+W/d^2)
        const float mu     = 0.5f * (__logf(d2) - sigma2);         // log(d)-s2/2
        const float amp    = fmaxf(__builtin_amdgcn_rsqf(sigma2) * cut * inv_d2,
                                   1.0e-30f);

        const float F  = -0.72134752f * __builtin_amdgcn_rcpf(sigma2); // -0.5*log2e/s2
        const float Fm = F * mu;
        const float c2 = fmaf(Fm, mu, __log2f(amp));

        const int s = (z == 1) ? 0 : (z - 5);
        const int slot = atomicAdd(&s_pos[la][s], 1);
        sP[la][slot] = make_float4(F, -(Fm + Fm), c2, dx * inv_d);
        sQ[la][slot] = make_float2(dy * inv_d, dz * inv_d);
    }
    __syncthreads();

    // -------- phase 2: thread = (atom, g-pair); accumulate T0/T1 ----------
    const int la = tid / 10;
    const int u  = tid - la * 10;
    const int atom = blockBase + la;
    const int g0 = 2 * u;

    const float off0 = 0.3f * (float)(g0 + 1);
    const float off1 = 0.3f * (float)(g0 + 2);
    const float lo0 = __logf(off0), lo1 = __logf(off1);
    const float q0 = lo0 * lo0,     q1 = lo1 * lo1;

    float T0[NSP_][10], T1[NSP_][10];
#pragma unroll
    for (int s = 0; s < NSP_; ++s)
#pragma unroll
        for (int a = 0; a < 10; ++a) { T0[s][a] = 0.0f; T1[s][a] = 0.0f; }

#define BODY(SS, P, Q)                                                        \
    {                                                                         \
        const float ea = fmaf(P.x, q0, fmaf(P.y, lo0, P.z));                  \
        const float eb = fmaf(P.x, q1, fmaf(P.y, lo1, P.z));                  \
        const float ra = __builtin_amdgcn_exp2f(ea);                          \
        const float rb = __builtin_amdgcn_exp2f(eb);                          \
        const float rax = ra * P.w, ray = ra * Q.x, raz = ra * Q.y;           \
        const float rbx = rb * P.w, rby = rb * Q.x, rbz = rb * Q.y;           \
        T0[SS][0] += ra;                                                      \
        T0[SS][1] += rax; T0[SS][2] += ray; T0[SS][3] += raz;                 \
        T0[SS][4] = fmaf(rax, P.w, T0[SS][4]);                                \
        T0[SS][5] = fmaf(rax, Q.x, T0[SS][5]);                                \
        T0[SS][6] = fmaf(ray, Q.x, T0[SS][6]);                                \
        T0[SS][7] = fmaf(rax, Q.y, T0[SS][7]);                                \
        T0[SS][8] = fmaf(ray, Q.y, T0[SS][8]);                                \
        T0[SS][9] = fmaf(raz, Q.y, T0[SS][9]);                                \
        T1[SS][0] += rb;                                                      \
        T1[SS][1] += rbx; T1[SS][2] += rby; T1[SS][3] += rbz;                 \
        T1[SS][4] = fmaf(rbx, P.w, T1[SS][4]);                                \
        T1[SS][5] = fmaf(rbx, Q.x, T1[SS][5]);                                \
        T1[SS][6] = fmaf(rby, Q.x, T1[SS][6]);                                \
        T1[SS][7] = fmaf(rbx, Q.y, T1[SS][7]);                                \
        T1[SS][8] = fmaf(rby, Q.y, T1[SS][8]);                                \
        T1[SS][9] = fmaf(rbz, Q.y, T1[SS][9]);                                \
    }

#define ACC(SS)                                                               \
    {                                                                         \
        const int e0 = s_start[la][SS];                                       \
        const int e1 = e0 + s_cnt[la][SS];                                    \
        int m = e0;                                                           \
        for (; m + 1 < e1; m += 2) {                                          \
            const float4 Pa = sP[la][m];     const float2 Qa = sQ[la][m];     \
            const float4 Pb = sP[la][m + 1]; const float2 Qb = sQ[la][m + 1]; \
            BODY(SS, Pa, Qa)                                                  \
            BODY(SS, Pb, Qb)                                                  \
        }                                                                     \
        if (m < e1) {                                                         \
            const float4 Pa = sP[la][m]; const float2 Qa = sQ[la][m];         \
            BODY(SS, Pa, Qa)                                                  \
        }                                                                     \
    }
    ACC(0) ACC(1) ACC(2) ACC(3)
#undef ACC
#undef BODY

    // -------- epilogue: 30 float2 stores (g0, g0+1) -----------------------
    const int n = atom & (N_ - 1);
    const float amask = (n < counts[bidx]) ? 1.0f : 0.0f;
    const float is0 = 1.0f / (off0 * 1.7724538509055159f);
    const float is1 = 1.0f / (off1 * 1.7724538509055159f);
    const float sc0 = amask * is0 * is0;
    const float sc1 = amask * is1 * is1;
    float* op = out + atom * FPSIZE_ + g0;

    // angw = [1, 1,1,1, 1,2,1,2,2,1]; lw = 1 for all l
#pragma unroll
    for (int l = 0; l < 3; ++l) {
        const int a0 = (l == 0) ? 0 : (l == 1) ? 1 : 4;
        const int a1 = (l == 0) ? 1 : (l == 1) ? 4 : 10;
#pragma unroll
        for (int s = 0; s < NSP_; ++s) {
            float v0 = 0.0f, v1 = 0.0f;
#pragma unroll
            for (int a = a0; a < a1; ++a) {
                const float w = (a == 5 || a == 7 || a == 8) ? 2.0f : 1.0f;
                v0 = fmaf(w * T0[s][a], T0[s][a], v0);
                v1 = fmaf(w * T1[s][a], T1[s][a], v1);
            }
            *(float2*)(op + (l * 10 + s) * NG_) = make_float2(sc0 * v0, sc1 * v1);
        }
        int mb = 4;
#pragma unroll
        for (int i = 0; i < NSP_; ++i) {
#pragma unroll
            for (int j = i + 1; j < NSP_; ++j) {
                float v0 = 0.0f, v1 = 0.0f;
#pragma unroll
                for (int a = a0; a < a1; ++a) {
                    const float w = (a == 5 || a == 7 || a == 8) ? 2.0f : 1.0f;
                    v0 = fmaf(w * T0[i][a], T0[j][a], v0);
                    v1 = fmaf(w * T1[i][a], T1[j][a], v1);
                }
                *(float2*)(op + (l * 10 + mb) * NG_) =
                    make_float2(sc0 * (2.0f * v0), sc1 * (2.0f * v1));
                ++mb;
            }
        }
    }
}

extern "C" void kernel_launch(void* const* d_in, const int* in_sizes, int n_in,
                              void* d_out, int out_size, void* d_ws, size_t ws_size,
                              hipStream_t stream) {
    const float* coords  = (const float*)d_in[0];
    const int*   charges = (const int*)d_in[1];
    const int*   counts  = (const int*)d_in[2];
    const int*   neigh   = (const int*)d_in[3];
    float*       outp    = (float*)d_out;

    const int blocks = (B_ * N_) / APB;   // 512
    gto_fp_kernel<<<blocks, BLOCK_THREADS, 0, stream>>>(coords, charges, counts, neigh, outp);
}